// Round 12
// baseline (22.373 us; speedup 1.0000x reference)
//
#include <hip/hip_runtime.h>

#define N_PTS 512
#define DIM 128
#define F4_PER_ROW 32
#define NCLASS 32
#define TLMARGIN 1.0f

// Leading zeroer: plain store (NOT hipMemsetAsync — rocclr fill has ~5us fixed
// cost in-graph, measured round 10). Runs before k_rows in-stream.
__global__ __launch_bounds__(64)
void k_zero(float* __restrict__ out) {
  if (threadIdx.x == 0) out[0] = 0.0f;
}

// 256 blocks x 512 threads; block b owns anchors {2b, 2b+1} (64MB total L2
// traffic — the 1-anchor/block variant doubled it and regressed, round 11).
// Phase 1: 8-lane cooperative dots from row-major input (R9-verified).
// Phase 2: register-resident mining (R11-verified): each wave holds the full
//   512-entry d-row + labels in 8 regs/lane; ballot masks identical per wave;
//   positives round-robin across 8 waves. No plist/pmask LDS, 2 barriers total.
// Tail: per-block class histogram -> C (identical in all blocks, R10-verified),
//   one atomicAdd(out, L/C) per block. No fences, no dependent reduce kernel.
__global__ __launch_bounds__(512)
void k_rows(const float* __restrict__ inp,
            const int* __restrict__ tgt,
            float* __restrict__ out) {
  const int i0 = blockIdx.x * 2;
  const int tid = threadIdx.x;
  const int lane = tid & 63;
  const int wave = tid >> 6;   // 0..7
  const int G = tid >> 3;      // 8-lane group id (0..63)
  const int s = tid & 7;       // lane within group

  __shared__ float d0[N_PTS];
  __shared__ float d1[N_PTS];
  __shared__ int lab[N_PTS];
  __shared__ int cnt[NCLASS];
  __shared__ float red[16];

  if (tid < NCLASS) cnt[tid] = 0;
  lab[tid] = tgt[tid];

  const float4* inp4 = reinterpret_cast<const float4*>(inp);

  // ---- anchor slice fragments (4 float4 per anchor per lane) + norms
  float4 a0f[4], a1f[4];
  float sa0 = 0.f, sa1 = 0.f;
#pragma unroll
  for (int q = 0; q < 4; ++q) {
    a0f[q] = inp4[i0 * F4_PER_ROW + q * 8 + s];
    a1f[q] = inp4[(i0 + 1) * F4_PER_ROW + q * 8 + s];
    sa0 += a0f[q].x * a0f[q].x + a0f[q].y * a0f[q].y + a0f[q].z * a0f[q].z + a0f[q].w * a0f[q].w;
    sa1 += a1f[q].x * a1f[q].x + a1f[q].y * a1f[q].y + a1f[q].z * a1f[q].z + a1f[q].w * a1f[q].w;
  }
#pragma unroll
  for (int off = 1; off <= 4; off <<= 1) {
    sa0 += __shfl_xor(sa0, off);
    sa1 += __shfl_xor(sa1, off);
  }

  // ---- pdist rows: group G handles j = r*64 + G, r = 0..7 (1KB/instr coalesced)
#pragma unroll 2
  for (int r = 0; r < 8; ++r) {
    const int j = r * 64 + G;
    float dot0 = 0.f, dot1 = 0.f, sj = 0.f;
#pragma unroll
    for (int q = 0; q < 4; ++q) {
      const float4 bv = inp4[j * F4_PER_ROW + q * 8 + s];
      dot0 += a0f[q].x * bv.x + a0f[q].y * bv.y + a0f[q].z * bv.z + a0f[q].w * bv.w;
      dot1 += a1f[q].x * bv.x + a1f[q].y * bv.y + a1f[q].z * bv.z + a1f[q].w * bv.w;
      sj   += bv.x * bv.x + bv.y * bv.y + bv.z * bv.z + bv.w * bv.w;
    }
#pragma unroll
    for (int off = 1; off <= 4; off <<= 1) {
      dot0 += __shfl_xor(dot0, off);
      dot1 += __shfl_xor(dot1, off);
      sj   += __shfl_xor(sj, off);
    }
    if (s == 0) {
      float pd0 = fmaxf(sa0 + sj - 2.0f * dot0, 0.0f);
      float pd1 = fmaxf(sa1 + sj - 2.0f * dot1, 0.0f);
      if (j == i0) pd0 = 0.0f;
      if (j == i0 + 1) pd1 = 0.0f;
      d0[j] = pd0;
      d1[j] = pd1;
    }
  }
  __syncthreads();                        // barrier 1: d, lab, cnt-zero visible

  atomicAdd(&cnt[lab[tid]], 1);           // LDS histogram (read after barrier 2)

  const int li0 = lab[i0];
  const int li1 = lab[i0 + 1];

  // ---- pull both d-rows + labels into registers: k = lane + kk*64
  float dk0[8], dk1[8];
  int lk[8];
#pragma unroll
  for (int kk = 0; kk < 8; ++kk) {
    const int k = lane + (kk << 6);
    dk0[kk] = d0[k];
    dk1[kk] = d1[k];
    lk[kk] = lab[k];
  }

  // ---- negatives_inside (row_min == 0 exactly)
  float nm0 = 0.0f, nm1 = 0.0f;
#pragma unroll
  for (int kk = 0; kk < 8; ++kk) {
    nm0 = (lk[kk] != li0) ? fmaxf(nm0, dk0[kk]) : nm0;
    nm1 = (lk[kk] != li1) ? fmaxf(nm1, dk1[kk]) : nm1;
  }
#pragma unroll
  for (int off = 32; off; off >>= 1) {
    nm0 = fmaxf(nm0, __shfl_xor(nm0, off));
    nm1 = fmaxf(nm1, __shfl_xor(nm1, off));
  }
  const float negin0 = nm0, negin1 = nm1;

  // ---- mine positives in-register, round-robin across the 8 waves
  float ls0 = 0.0f, ls1 = 0.0f;
  int rank0 = 0, rank1 = 0;
#pragma unroll
  for (int kk = 0; kk < 8; ++kk) {
    const int k = lane + (kk << 6);
    unsigned long long m0 = __ballot((lk[kk] == li0) && (k != i0));
    while (m0) {
      const int b = __ffsll(m0) - 1;
      m0 &= m0 - 1;
      if (((rank0++) & 7) == wave) {        // wave-uniform predicate
        const float dj = __shfl(dk0[kk], b);
        float mn = __builtin_inff();
#pragma unroll
        for (int k2 = 0; k2 < 8; ++k2) {
          const bool ok = (lk[k2] != li0) && (dk0[k2] > dj);
          mn = ok ? fminf(mn, dk0[k2]) : mn;
        }
#pragma unroll
        for (int off = 32; off; off >>= 1) mn = fminf(mn, __shfl_xor(mn, off));
        const float shn = (mn < __builtin_inff()) ? mn : negin0;
        ls0 += fmaxf(TLMARGIN + dj - shn, 0.0f);
      }
    }
    unsigned long long m1 = __ballot((lk[kk] == li1) && (k != i0 + 1));
    while (m1) {
      const int b = __ffsll(m1) - 1;
      m1 &= m1 - 1;
      if (((rank1++) & 7) == wave) {
        const float dj = __shfl(dk1[kk], b);
        float mn = __builtin_inff();
#pragma unroll
        for (int k2 = 0; k2 < 8; ++k2) {
          const bool ok = (lk[k2] != li1) && (dk1[k2] > dj);
          mn = ok ? fminf(mn, dk1[k2]) : mn;
        }
#pragma unroll
        for (int off = 32; off; off >>= 1) mn = fminf(mn, __shfl_xor(mn, off));
        const float shn = (mn < __builtin_inff()) ? mn : negin1;
        ls1 += fmaxf(TLMARGIN + dj - shn, 0.0f);
      }
    }
  }

  // ---- block tail: reduce 8 waves, divide by C, one atomic
  if (lane == 0) { red[wave] = ls0; red[8 + wave] = ls1; }
  __syncthreads();                        // barrier 2: red + histogram complete
  if (tid == 0) {
    float L = 0.0f;
#pragma unroll
    for (int w = 0; w < 8; ++w) L += red[w] + red[8 + w];
    int C = 0;
#pragma unroll
    for (int c = 0; c < NCLASS; ++c) C += cnt[c] * (cnt[c] - 1);
    atomicAdd(out, L / (float)C);         // sum over blocks == total/num_positives
  }
}

extern "C" void kernel_launch(void* const* d_in, const int* in_sizes, int n_in,
                              void* d_out, int out_size, void* d_ws, size_t ws_size,
                              hipStream_t stream) {
  const float* inp = (const float*)d_in[0];
  const int* tgt = (const int*)d_in[1];
  float* out = (float*)d_out;

  k_zero<<<1, 64, 0, stream>>>(out);
  k_rows<<<N_PTS / 2, 512, 0, stream>>>(inp, tgt, out);
}

// Round 13
// 15.910 us; speedup vs baseline: 1.4062x; 1.4062x over previous
//
#include <hip/hip_runtime.h>

#define N_PTS 512
#define DIM 128
#define F4_PER_ROW 32
#define TLMARGIN 1.0f

// K1: 256 blocks x 512 threads; block b owns anchors {2b, 2b+1}.
// (R9-verified structure, 16.0us — every structural variant measured worse:
//  cooperative R4, fused R6, ticket+fence R7 (+4.4us), atomic tails R10/R12
//  (+4.5us), 1-anchor blocks R11 (+2.4us, 2x L2 traffic).)
// Phase 1: 8-lane cooperative dots directly from row-major input: lane s of
//   group G reads float4 slice q*8+s -> each instruction reads 1KB contiguous.
//   unroll 4: 16 float4 loads in flight to hide L2-hit latency at 2 waves/SIMD.
// Phase 2: semi-hard mining for both rows (verified R8/R9 code).
__global__ __launch_bounds__(512)
void k_rows(const float* __restrict__ inp,
            const int* __restrict__ tgt,
            float2* __restrict__ rl) {
  const int i0 = blockIdx.x * 2;
  const int tid = threadIdx.x;
  const int lane = tid & 63;
  const int wave = tid >> 6;
  const int G = tid >> 3;   // 8-lane group id (0..63)
  const int s = tid & 7;    // lane within group

  __shared__ float d[2][N_PTS];
  __shared__ int lab[N_PTS];
  __shared__ float red[32];
  __shared__ unsigned long long pm0[8];
  __shared__ unsigned long long pm1[8];
  __shared__ int plist0[N_PTS];
  __shared__ int plist1[N_PTS];

  lab[tid] = tgt[tid];

  const float4* inp4 = reinterpret_cast<const float4*>(inp);

  // ---- anchor slice fragments (4 float4 per anchor per lane) + norms
  float4 a0f[4], a1f[4];
  float sa0 = 0.f, sa1 = 0.f;
#pragma unroll
  for (int q = 0; q < 4; ++q) {
    a0f[q] = inp4[i0 * F4_PER_ROW + q * 8 + s];
    a1f[q] = inp4[(i0 + 1) * F4_PER_ROW + q * 8 + s];
    sa0 += a0f[q].x * a0f[q].x + a0f[q].y * a0f[q].y + a0f[q].z * a0f[q].z + a0f[q].w * a0f[q].w;
    sa1 += a1f[q].x * a1f[q].x + a1f[q].y * a1f[q].y + a1f[q].z * a1f[q].z + a1f[q].w * a1f[q].w;
  }
#pragma unroll
  for (int off = 1; off <= 4; off <<= 1) {
    sa0 += __shfl_xor(sa0, off);
    sa1 += __shfl_xor(sa1, off);
  }

  // ---- pdist rows: group G handles j = r*64 + G, r = 0..7
#pragma unroll 4
  for (int r = 0; r < 8; ++r) {
    const int j = r * 64 + G;
    float dot0 = 0.f, dot1 = 0.f, sj = 0.f;
#pragma unroll
    for (int q = 0; q < 4; ++q) {
      const float4 bv = inp4[j * F4_PER_ROW + q * 8 + s];  // 1KB/instr per wave
      dot0 += a0f[q].x * bv.x + a0f[q].y * bv.y + a0f[q].z * bv.z + a0f[q].w * bv.w;
      dot1 += a1f[q].x * bv.x + a1f[q].y * bv.y + a1f[q].z * bv.z + a1f[q].w * bv.w;
      sj   += bv.x * bv.x + bv.y * bv.y + bv.z * bv.z + bv.w * bv.w;
    }
#pragma unroll
    for (int off = 1; off <= 4; off <<= 1) {
      dot0 += __shfl_xor(dot0, off);
      dot1 += __shfl_xor(dot1, off);
      sj   += __shfl_xor(sj, off);
    }
    if (s == 0) {
      float pd0 = fmaxf(sa0 + sj - 2.0f * dot0, 0.0f);
      float pd1 = fmaxf(sa1 + sj - 2.0f * dot1, 0.0f);
      if (j == i0) pd0 = 0.0f;
      if (j == i0 + 1) pd1 = 0.0f;
      d[0][j] = pd0;
      d[1][j] = pd1;
    }
  }
  __syncthreads();                                    // publish d + lab

  const int li0 = lab[i0];
  const int li1 = lab[i0 + 1];

  // ---- per-wave max over negatives + positive ballots for BOTH rows
  const float d0t = d[0][tid];
  const float d1t = d[1][tid];
  float nm0 = (lab[tid] != li0) ? d0t : 0.0f;
  float nm1 = (lab[tid] != li1) ? d1t : 0.0f;
#pragma unroll
  for (int off = 32; off; off >>= 1) {
    nm0 = fmaxf(nm0, __shfl_xor(nm0, off));
    nm1 = fmaxf(nm1, __shfl_xor(nm1, off));
  }
  const bool isPos0 = (lab[tid] == li0) && (tid != i0);
  const bool isPos1 = (lab[tid] == li1) && (tid != i0 + 1);
  const unsigned long long m0 = __ballot(isPos0);
  const unsigned long long m1 = __ballot(isPos1);
  if (lane == 0) {
    red[wave] = nm0;
    red[8 + wave] = nm1;
    pm0[wave] = m0;
    pm1[wave] = m1;
  }
  __syncthreads();                                    // publish red, pm

  float negin0 = red[0], negin1 = red[8];
#pragma unroll
  for (int w = 1; w < 8; ++w) {
    negin0 = fmaxf(negin0, red[w]);
    negin1 = fmaxf(negin1, red[8 + w]);
  }

  int P0 = 0, rank0 = 0, P1 = 0, rank1 = 0;
#pragma unroll
  for (int w = 0; w < 8; ++w) {
    const int c0 = __popcll(pm0[w]);
    const int c1 = __popcll(pm1[w]);
    if (w < wave) { rank0 += c0; rank1 += c1; }
    P0 += c0;
    P1 += c1;
  }
  rank0 += __popcll(pm0[wave] & ((1ull << lane) - 1ull));
  rank1 += __popcll(pm1[wave] & ((1ull << lane) - 1ull));
  if (isPos0) plist0[rank0] = tid;
  if (isPos1) plist1[rank1] = tid;
  __syncthreads();                                    // publish plists

  // ---- mine both rows: wave w takes entries w, w+8, ...
  float ls0 = 0.0f, pc0 = 0.0f, ls1 = 0.0f, pc1 = 0.0f;
  for (int p = wave; p < P0; p += 8) {
    const int j = plist0[p];
    const float dj = d[0][j];
    float mn = __builtin_inff();
#pragma unroll
    for (int kk = 0; kk < N_PTS / 64; ++kk) {
      const int k = lane + (kk << 6);
      const float dk = d[0][k];
      if (lab[k] != li0 && dk > dj) mn = fminf(mn, dk);
    }
#pragma unroll
    for (int off = 32; off; off >>= 1) mn = fminf(mn, __shfl_xor(mn, off));
    const float shn = (mn < __builtin_inff()) ? mn : negin0;
    ls0 += fmaxf(TLMARGIN + dj - shn, 0.0f);
    pc0 += 1.0f;
  }
  for (int p = wave; p < P1; p += 8) {
    const int j = plist1[p];
    const float dj = d[1][j];
    float mn = __builtin_inff();
#pragma unroll
    for (int kk = 0; kk < N_PTS / 64; ++kk) {
      const int k = lane + (kk << 6);
      const float dk = d[1][k];
      if (lab[k] != li1 && dk > dj) mn = fminf(mn, dk);
    }
#pragma unroll
    for (int off = 32; off; off >>= 1) mn = fminf(mn, __shfl_xor(mn, off));
    const float shn = (mn < __builtin_inff()) ? mn : negin1;
    ls1 += fmaxf(TLMARGIN + dj - shn, 0.0f);
    pc1 += 1.0f;
  }

  if (lane == 0) {
    red[wave] = ls0;
    red[8 + wave] = pc0;
    red[16 + wave] = ls1;
    red[24 + wave] = pc1;
  }
  __syncthreads();
  if (tid == 0) {
    float a = 0.f, b = 0.f, c = 0.f, e = 0.f;
#pragma unroll
    for (int w = 0; w < 8; ++w) {
      a += red[w];
      b += red[8 + w];
      c += red[16 + w];
      e += red[24 + w];
    }
    rl[i0] = make_float2(a, b);
    rl[i0 + 1] = make_float2(c, e);
  }
}

// K2: 1 block x 256 threads -> scalar loss
__global__ __launch_bounds__(256)
void k_reduce(const float2* __restrict__ rl, float* __restrict__ out) {
  __shared__ float red[8];
  const int tid = threadIdx.x;
  const float2 a = rl[tid];
  const float2 b = rl[tid + 256];
  float l = a.x + b.x;
  float c = a.y + b.y;
#pragma unroll
  for (int off = 32; off; off >>= 1) {
    l += __shfl_xor(l, off);
    c += __shfl_xor(c, off);
  }
  const int lane = tid & 63, wave = tid >> 6;
  if (lane == 0) { red[wave] = l; red[4 + wave] = c; }
  __syncthreads();
  if (tid == 0) {
    float L = 0.0f, C = 0.0f;
#pragma unroll
    for (int w = 0; w < 4; ++w) { L += red[w]; C += red[4 + w]; }
    out[0] = L / C;
  }
}

extern "C" void kernel_launch(void* const* d_in, const int* in_sizes, int n_in,
                              void* d_out, int out_size, void* d_ws, size_t ws_size,
                              hipStream_t stream) {
  const float* inp = (const float*)d_in[0];
  const int* tgt = (const int*)d_in[1];
  float* out = (float*)d_out;

  float2* rl = (float2*)d_ws;   // 4 KB

  k_rows<<<N_PTS / 2, 512, 0, stream>>>(inp, tgt, rl);
  k_reduce<<<1, 256, 0, stream>>>(rl, out);
}